// Round 3
// baseline (1391.624 us; speedup 1.0000x reference)
//
#include <hip/hip_runtime.h>
#include <hip/hip_bf16.h>
#include <stdint.h>

// Fully fused QMIX+GAT. Kernel P packs hypernet weights -> bf16 MFMA B-frags
// (360KB in d_ws). Kernel F: per block (32 samples, 4 waves): GAT in VALU ->
// s bf16 in swizzled LDS -> MFMA GEMM s@[hw1|hb1|hwf|v1] -> mixing epilogue.
// Output: float32 (reference output dtype).

#define N_AGENTS 8
#define NODE     16
#define FEAT     16
#define NHID     4
#define NHEADS   4
#define GOUT     32
#define EMBED    32
#define LAYER_IN 512
#define BT       (2048 * 128)
#define ALPHA    0.2f
#define NTILE    22            // 352 / 16
#define KSTEPS   16            // 512 / 32

typedef __attribute__((ext_vector_type(8))) short bf16x8;
typedef __attribute__((ext_vector_type(4))) float f32x4;

__device__ __forceinline__ float leaky(float x) { return x >= 0.f ? x : ALPHA * x; }
__device__ __forceinline__ float elu1(float x)  { return x > 0.f ? x : (__expf(x) - 1.f); }

__device__ __forceinline__ unsigned short f32_to_bf16_rne(float x) {
    uint32_t u = __float_as_uint(x);
    u += 0x7fffu + ((u >> 16) & 1u);
    return (unsigned short)(u >> 16);
}

// -------------------------------------------------- kernel P: pack B (bf16 frags)
// B[512][352] cols: 0..255 hw1 | 256..287 hb1 | 288..319 hwf | 320..351 v1.
// Frag (kt, ni): 64 lanes x 16B; lane l elem e -> B[kt*32+(l>>4)*8+e][ni*16+(l&15)]
__global__ __launch_bounds__(256) void pack_b(
    const float* __restrict__ hw1_w, const float* __restrict__ hb1_w,
    const float* __restrict__ hwf_w, const float* __restrict__ v1_w,
    unsigned short* __restrict__ bpack)
{
    const int g = blockIdx.x * 256 + threadIdx.x;   // 16*22*64 = 22528 frag-lanes
    if (g >= KSTEPS * NTILE * 64) return;
    const int l  = g & 63;
    const int ni = (g >> 6) % NTILE;
    const int kt = g / (NTILE * 64);
    const int col = ni * 16 + (l & 15);
    const int k0  = kt * 32 + (l >> 4) * 8;
    const float* src; int stride; int c;
    if (col < 256)      { src = hw1_w; stride = 256; c = col; }
    else if (col < 288) { src = hb1_w; stride = 32;  c = col - 256; }
    else if (col < 320) { src = hwf_w; stride = 32;  c = col - 288; }
    else                { src = v1_w;  stride = 32;  c = col - 320; }
    union { unsigned short u[8]; uint4 v; } pk;
    #pragma unroll
    for (int e = 0; e < 8; ++e) pk.u[e] = f32_to_bf16_rne(src[(long)(k0 + e) * stride + c]);
    ((uint4*)bpack)[g] = pk.v;
}

// -------------------------------------------------- kernel F: fused GAT+GEMM+mix
__global__ __launch_bounds__(256) void fused_kernel(
    const float* __restrict__ agent_qs, const float* __restrict__ states,
    const float* __restrict__ W_heads,  const float* __restrict__ a_heads,
    const float* __restrict__ W_out,    const float* __restrict__ a_out,
    const unsigned short* __restrict__ bpack,
    const float* __restrict__ hw1_b, const float* __restrict__ hb1_b,
    const float* __restrict__ hwf_b, const float* __restrict__ v1_b,
    const float* __restrict__ v2_w,  const float* __restrict__ v2_b,
    float* __restrict__ out)
{
    __shared__ union {
        struct {
            unsigned short A[32][512];   // s-tile bf16, row-XOR-swizzled (32KB)
            float sc[4][1408];           // per-wave GAT scratch (22KB)
        } p1;
        struct {
            float hyp[32][356];          // hypernet pre-activation (45.6KB)
        } p2;
    } u;
    __shared__ float gw[864];            // Wh[256] ah[32] Wo[512] ao[64]
    __shared__ float qs_s[32][8];
    __shared__ float cont[32][32];
    __shared__ float vw_s[32];

    const int t    = threadIdx.x;
    const int w    = t >> 6;
    const int lane = t & 63;
    const long sbase = (long)blockIdx.x * 32;

    for (int i = t; i < 864; i += 256) {
        float v;
        if (i < 256)      v = W_heads[i];
        else if (i < 288) v = a_heads[i - 256];
        else if (i < 800) v = W_out[i - 288];
        else              v = a_out[i - 800];
        gw[i] = v;
    }
    qs_s[t >> 3][t & 7] = agent_qs[sbase * 8 + t];
    if (t < 32) vw_s[t] = v2_w[t];

    // GAT scratch views (per wave)
    float* sc = u.p1.sc[w];
    #define XS(n,f)   sc[(n)*17 + (f)]
    #define WHS(n,k)  sc[272 + (n)*4 + (k)]
    #define ATTS(n,j) sc[336 + (n)*17 + (j)]
    #define HCAT(n,f) sc[608 + (n)*17 + (f)]
    #define WH2(n,c)  sc[880 + (n)*33 + (c)]
    #define GW_WH(h,f,k) gw[(h)*64 + (f)*4 + (k)]
    #define GW_AH(h,i)   gw[256 + (h)*8 + (i)]
    #define GW_WO(f,c)   gw[288 + (f)*32 + (c)]
    #define GW_AO(c)     gw[800 + (c)]

    __syncthreads();

    const int n  = lane >> 2;   // node row 0..15
    const int kq = lane & 3;    // quarter index 0..3

    // ---------------- phase 1: GAT, 8 samples per wave, sequential
    for (int i = 0; i < 8; ++i) {
        const int m = w * 8 + i;                 // sample within block
        const long gs = sbase + m;
        const float4 xv = ((const float4*)(states + gs * 256))[lane];
        XS(n, kq * 4 + 0) = xv.x;
        XS(n, kq * 4 + 1) = xv.y;
        XS(n, kq * 4 + 2) = xv.z;
        XS(n, kq * 4 + 3) = xv.w;

        for (int h = 0; h < NHEADS; ++h) {
            float wh = 0.f;
            #pragma unroll
            for (int f = 0; f < 16; ++f) wh = fmaf(XS(n, f), GW_WH(h, f, kq), wh);
            WHS(n, kq) = wh;

            float p1 = wh * GW_AH(h, kq);
            float p2 = wh * GW_AH(h, 4 + kq);
            p1 += __shfl_xor(p1, 1); p1 += __shfl_xor(p1, 2);   // e1[n]
            p2 += __shfl_xor(p2, 1); p2 += __shfl_xor(p2, 2);   // e2[n]

            float ev[4]; float mx = -1e30f;
            #pragma unroll
            for (int q = 0; q < 4; ++q) {
                const int j = 4 * kq + q;
                ev[q] = leaky(p1 + __shfl(p2, j * 4));
                mx = fmaxf(mx, ev[q]);
            }
            mx = fmaxf(mx, __shfl_xor(mx, 1));
            mx = fmaxf(mx, __shfl_xor(mx, 2));
            float sum = 0.f;
            #pragma unroll
            for (int q = 0; q < 4; ++q) { ev[q] = __expf(ev[q] - mx); sum += ev[q]; }
            sum += __shfl_xor(sum, 1); sum += __shfl_xor(sum, 2);
            const float inv = 1.f / sum;
            #pragma unroll
            for (int q = 0; q < 4; ++q) ATTS(n, 4 * kq + q) = ev[q] * inv;

            float ho = 0.f;
            #pragma unroll
            for (int j = 0; j < 16; ++j) ho = fmaf(ATTS(n, j), WHS(j, kq), ho);
            HCAT(n, h * 4 + kq) = elu1(ho);
        }

        // output GAT layer
        float wh2[8];
        #pragma unroll
        for (int c8 = 0; c8 < 8; ++c8) {
            const int c = kq * 8 + c8;
            float acc = 0.f;
            #pragma unroll
            for (int f = 0; f < 16; ++f) acc = fmaf(HCAT(n, f), GW_WO(f, c), acc);
            wh2[c8] = acc;
            WH2(n, c) = acc;
        }
        float p1 = 0.f, p2 = 0.f;
        #pragma unroll
        for (int c8 = 0; c8 < 8; ++c8) {
            const int c = kq * 8 + c8;
            p1 = fmaf(wh2[c8], GW_AO(c), p1);
            p2 = fmaf(wh2[c8], GW_AO(32 + c), p2);
        }
        p1 += __shfl_xor(p1, 1); p1 += __shfl_xor(p1, 2);
        p2 += __shfl_xor(p2, 1); p2 += __shfl_xor(p2, 2);

        float ev[4]; float mx = -1e30f;
        #pragma unroll
        for (int q = 0; q < 4; ++q) {
            const int j = 4 * kq + q;
            ev[q] = leaky(p1 + __shfl(p2, j * 4));
            mx = fmaxf(mx, ev[q]);
        }
        mx = fmaxf(mx, __shfl_xor(mx, 1));
        mx = fmaxf(mx, __shfl_xor(mx, 2));
        float sum = 0.f;
        #pragma unroll
        for (int q = 0; q < 4; ++q) { ev[q] = __expf(ev[q] - mx); sum += ev[q]; }
        sum += __shfl_xor(sum, 1); sum += __shfl_xor(sum, 2);
        const float inv = 1.f / sum;
        #pragma unroll
        for (int q = 0; q < 4; ++q) ATTS(n, 4 * kq + q) = ev[q] * inv;

        union { unsigned short us[8]; uint4 v; } pk;
        #pragma unroll
        for (int c8 = 0; c8 < 8; ++c8) {
            const int c = kq * 8 + c8;
            float acc = 0.f;
            #pragma unroll
            for (int j = 0; j < 16; ++j) acc = fmaf(ATTS(n, j), WH2(j, c), acc);
            pk.us[c8] = f32_to_bf16_rne(elu1(acc));
        }
        // s[n*32 + kq*8 .. +7] -> row m, byte (n*64+kq*16) ^ ((m&7)<<4)
        *(uint4*)((char*)&u.p1.A[m][0] + ((n * 64 + kq * 16) ^ ((m & 7) << 4))) = pk.v;
    }

    __syncthreads();

    // ---------------- phase 2: MFMA GEMM  s[32x512] @ B[512x352]
    const int mi  = w >> 1;             // m-tile 0..1
    const int ni0 = (w & 1) * 11;       // first of 11 n-tiles
    f32x4 acc[11];
    #pragma unroll
    for (int j = 0; j < 11; ++j) acc[j] = (f32x4){0.f, 0.f, 0.f, 0.f};

    const int arow = mi * 16 + (lane & 15);
    const int kbyt = (lane >> 4) * 16;  // byte offset of this lane's 8 k-elems
    const char* Abase = (const char*)&u.p1.A[0][0] + arow * 1024;
    const uint4* Bbase = (const uint4*)bpack + (long)ni0 * 64 + lane;

    for (int kt = 0; kt < KSTEPS; ++kt) {
        const bf16x8 af = *(const bf16x8*)(Abase + ((kt * 64 + kbyt) ^ ((arow & 7) << 4)));
        const uint4* bp = Bbase + (long)kt * NTILE * 64;
        #pragma unroll
        for (int j = 0; j < 11; ++j) {
            uint4 bw = bp[j * 64];
            bf16x8 bf;
            memcpy(&bf, &bw, 16);
            acc[j] = __builtin_amdgcn_mfma_f32_16x16x32_bf16(af, bf, acc[j], 0, 0, 0);
        }
    }

    __syncthreads();   // A-tile dead; union flips to hyp

    #pragma unroll
    for (int j = 0; j < 11; ++j) {
        const int col = (ni0 + j) * 16 + (lane & 15);
        const int r0  = mi * 16 + (lane >> 4) * 4;
        #pragma unroll
        for (int r = 0; r < 4; ++r) u.p2.hyp[r0 + r][col] = acc[j][r];
    }
    __syncthreads();

    // ---------------- phase 3: mixing epilogue
    {
        const int m = t >> 5, e = t & 31;           // 256 threads -> 8 m x 32 e, x4
        #pragma unroll
        for (int mm = 0; mm < 4; ++mm) {
            const int ms = m + mm * 8;
            float hs = u.p2.hyp[ms][256 + e] + hb1_b[e];
            #pragma unroll
            for (int a = 0; a < 8; ++a)
                hs = fmaf(qs_s[ms][a], fabsf(u.p2.hyp[ms][a * 32 + e] + hw1_b[a * 32 + e]), hs);
            const float hid = elu1(hs);
            const float wf  = fabsf(u.p2.hyp[ms][288 + e] + hwf_b[e]);
            const float v1  = fmaxf(u.p2.hyp[ms][320 + e] + v1_b[e], 0.f);
            cont[ms][e] = hid * wf + v1 * vw_s[e];
        }
    }
    __syncthreads();

    if (t < 32) {
        float y = 0.f;
        #pragma unroll
        for (int e = 0; e < 32; ++e) y += cont[t][(t + e) & 31];
        out[sbase + t] = y + v2_b[0];   // f32 store (reference output dtype)
    }
}

// -------------------------------------------------- launch
extern "C" void kernel_launch(void* const* d_in, const int* in_sizes, int n_in,
                              void* d_out, int out_size, void* d_ws, size_t ws_size,
                              hipStream_t stream) {
    const float* agent_qs = (const float*)d_in[0];
    const float* states   = (const float*)d_in[1];
    const float* W_heads  = (const float*)d_in[2];
    const float* a_heads  = (const float*)d_in[3];
    const float* W_out    = (const float*)d_in[4];
    const float* a_out    = (const float*)d_in[5];
    const float* hw1_b    = (const float*)d_in[7];
    const float* hb1_b    = (const float*)d_in[9];
    const float* hwf_b    = (const float*)d_in[11];
    const float* v1_b     = (const float*)d_in[13];
    const float* v2_w     = (const float*)d_in[14];
    const float* v2_b     = (const float*)d_in[15];
    const float* hw1_w    = (const float*)d_in[6];
    const float* hb1_w    = (const float*)d_in[8];
    const float* hwf_w    = (const float*)d_in[10];
    const float* v1_w     = (const float*)d_in[12];

    unsigned short* bpack = (unsigned short*)d_ws;   // 360448 B used

    pack_b<<<(KSTEPS * NTILE * 64 + 255) / 256, 256, 0, stream>>>(hw1_w, hb1_w, hwf_w, v1_w, bpack);
    fused_kernel<<<BT / 32, 256, 0, stream>>>(agent_qs, states,
                                              W_heads, a_heads, W_out, a_out,
                                              bpack,
                                              hw1_b, hb1_b, hwf_b, v1_b, v2_w, v2_b,
                                              (float*)d_out);
}